// Round 5
// baseline (853.931 us; speedup 1.0000x reference)
//
#include <hip/hip_runtime.h>

#define NVEL  400
#define PMLW  20
#define NSIDE 440
#define BATCH 4
#define NT    100
#define NREC  100

#define TS 55              // tile side; 8x8 tiles x 4 batches = 256 blocks (1/CU)
#define GT 8
#define WP 65              // wf LDS pitch
#define PYP 56             // psiy rows -2..56 (59) x cols 0..54
#define PXP 60             // psix rows 0..54 x cols -2..56 (59)
#define ZP  56

#define C1f (1.0f/48.0f)   // 1/(12*dh)
#define C2f (1.0f/192.0f)  // 1/(12*dh*dh)
#define NTH 1024

#define WIDX(y,x) (((y)+4)*WP + ((x)+4))

__global__ __launch_bounds__(NTH, 1) void kWave(
    const float* __restrict__ v, const float* __restrict__ amp,
    const int* __restrict__ sloc, const int* __restrict__ rloc,
    float* __restrict__ out, int* __restrict__ flags, float* __restrict__ strips)
{
    __shared__ float sWF0[63*WP], sWF1[63*WP];
    __shared__ float sPY[59*PYP];
    __shared__ float sPX[TS*PXP];
    __shared__ float sZY[TS*ZP], sZX[TS*ZP], sV2[TS*ZP];
    __shared__ float pa_y[63], pb_y[63], pa_x[63], pb_x[63];
    __shared__ float sAmp[NT];

    const int tid  = threadIdx.x;
    const int lane = tid & 63;
    const int wrow = tid >> 6;          // 0..15
    const int bid = blockIdx.x;
    const int b   = bid >> 6;
    const int tl  = bid & 63;
    const int tyi = tl >> 3, txi = tl & 7;
    const int by0 = tyi*TS, bx0 = txi*TS;
    const int nbN = (tyi > 0)    ? bid - GT : -1;
    const int nbS = (tyi < GT-1) ? bid + GT : -1;
    const int nbW = (txi > 0)    ? bid - 1  : -1;
    const int nbE = (txi < GT-1) ? bid + 1  : -1;

    // ---- init LDS state ----
    for (int i = tid; i < 63*WP; i += NTH) { sWF0[i] = 0.f; sWF1[i] = 0.f; }
    for (int i = tid; i < 59*PYP; i += NTH) sPY[i] = 0.f;
    for (int i = tid; i < TS*PXP; i += NTH) sPX[i] = 0.f;
    for (int i = tid; i < TS*ZP; i += NTH) { sZY[i] = 0.f; sZX[i] = 0.f; }
    for (int i = tid; i < TS*TS; i += NTH) {
        int y = i/TS, x = i - y*TS;
        int cy = min(max(by0 + y - PMLW, 0), NVEL-1);
        int cx = min(max(bx0 + x - PMLW, 0), NVEL-1);
        float vv = v[cy*NVEL + cx];
        sV2[y*ZP + x] = vv*vv*(float)(0.0008*0.0008);
    }
    if (tid < 63) {
        const float smax = (float)(3.0*2600.0*6.907755278982137/160.0);
        float gy = (float)(by0 + tid - 4);
        float dy = fmaxf(fminf(fmaxf((20.f-gy)/20.f,0.f),1.f),
                         fminf(fmaxf((gy-419.f)/20.f,0.f),1.f));
        float bby = expf(-smax*dy*dy*0.0008f);
        pb_y[tid] = bby; pa_y[tid] = bby - 1.f;
        float gx = (float)(bx0 + tid - 4);
        float dx = fmaxf(fminf(fmaxf((20.f-gx)/20.f,0.f),1.f),
                         fminf(fmaxf((gx-419.f)/20.f,0.f),1.f));
        float bbx = expf(-smax*dx*dx*0.0008f);
        pb_x[tid] = bbx; pa_x[tid] = bbx - 1.f;
    }
    if (tid < NT) sAmp[tid] = amp[b*NT + tid];

    const int sly = sloc[b*2]   + PMLW - by0;
    const int slx = sloc[b*2+1] + PMLW - bx0;

    int rofs = -1, rIdx = 0;
    if (tid < NREC) {
        int gry = rloc[(b*NREC+tid)*2]   + PMLW;
        int grx = rloc[(b*NREC+tid)*2+1] + PMLW;
        if (gry >= by0 && gry < by0+TS && grx >= bx0 && grx < bx0+TS) {
            rofs = (b*NREC+tid)*NT;
            rIdx = WIDX(gry-by0, grx-bx0);
        }
    }

    // import/export descriptors. Slots: 0=rows0..3, 1=rows51..54 (c-fast),
    // 2=cols0..3, 3=cols51..54 (r-fast). 220 elems each.
    int imp_nb = -1, imp_src = 0, imp_dst = 0, exp_src = 0;
    if (tid < 880) {
        int e = tid/220, j = tid - e*220;
        if (e == 0)      { int r=j/55, c=j-55*r; imp_nb=nbN; imp_src=1*220+j; imp_dst=WIDX(r-4,c);   exp_src=WIDX(r,c); }
        else if (e == 1) { int r=j/55, c=j-55*r; imp_nb=nbS; imp_src=0*220+j; imp_dst=WIDX(55+r,c);  exp_src=WIDX(51+r,c); }
        else if (e == 2) { int r=j&3,  c=j>>2;   imp_nb=nbW; imp_src=3*220+j; imp_dst=WIDX(c,r-4);   exp_src=WIDX(c,r); }
        else             { int r=j&3,  c=j>>2;   imp_nb=nbE; imp_src=2*220+j; imp_dst=WIDX(c,55+r);  exp_src=WIDX(c,51+r); }
    }
    __syncthreads();

    float* cur = sWF0;
    float* nxt = sWF1;

    for (int t = 0; t < NT; ++t) {
        // ---- import neighbor halo strips of cur (exported end of t-1) ----
        if (t > 0 && imp_nb >= 0) {
            int spin = 0;
            while (__hip_atomic_load(&flags[imp_nb], __ATOMIC_RELAXED,
                                     __HIP_MEMORY_SCOPE_AGENT) < t
                   && spin < 2000000) { __builtin_amdgcn_s_sleep(1); ++spin; }
            asm volatile("" ::: "memory");
            cur[imp_dst] = __hip_atomic_load(
                &strips[(size_t)(((t-1)&1)*256 + imp_nb)*880 + imp_src],
                __ATOMIC_RELAXED, __HIP_MEMORY_SCOPE_AGENT);
        }
        __syncthreads();

        // ---- psi pass: psiy rows -2..56 x cols 0..54; psix rows 0..54 x cols -2..56
        #pragma unroll
        for (int k = 0; k < 4; ++k) {
            int ri = wrow + 16*k;               // row index 0..58 -> r = ri-2
            if (ri < 59 && lane < 55) {
                int r = ri - 2;
                int w = WIDX(r, lane);
                float d1 = (cur[w-2*WP] - cur[w+2*WP]
                            + 8.f*(cur[w+WP] - cur[w-WP])) * C1f;
                int gy = by0 + r;
                int pi = ri*PYP + lane;
                float val = 0.f;
                if (gy >= 0 && gy < NSIDE)
                    val = pb_y[r+4]*sPY[pi] + pa_y[r+4]*d1;
                sPY[pi] = val;
            }
        }
        #pragma unroll
        for (int k = 0; k < 4; ++k) {
            int y = wrow + 16*k;
            if (y < 55 && lane < 59) {
                int c = lane - 2;
                int w = WIDX(y, c);
                float d1 = (cur[w-2] - cur[w+2]
                            + 8.f*(cur[w+1] - cur[w-1])) * C1f;
                int gx = bx0 + c;
                int pi = y*PXP + lane;
                float val = 0.f;
                if (gx >= 0 && gx < NSIDE)
                    val = pb_x[c+4]*sPX[pi] + pa_x[c+4]*d1;
                sPX[pi] = val;
            }
        }
        __syncthreads();

        // ---- interior pass: all 55x55 cells ----
        #pragma unroll
        for (int k = 0; k < 4; ++k) {
            int y = wrow + 16*k;
            if (y < 55 && lane < 55) {
                int x = lane;
                int w = WIDX(y, x);
                float wc = cur[w];
                float d2y = (-(cur[w-2*WP] + cur[w+2*WP])
                             + 16.f*(cur[w-WP] + cur[w+WP]) - 30.f*wc) * C2f
                          + (sPY[y*PYP+x] - sPY[(y+4)*PYP+x]
                             + 8.f*(sPY[(y+3)*PYP+x] - sPY[(y+1)*PYP+x])) * C1f;
                float d2x = (-(cur[w-2] + cur[w+2])
                             + 16.f*(cur[w-1] + cur[w+1]) - 30.f*wc) * C2f
                          + (sPX[y*PXP+x] - sPX[y*PXP+x+4]
                             + 8.f*(sPX[y*PXP+x+3] - sPX[y*PXP+x+1])) * C1f;
                int zi = y*ZP + x;
                float zy = pb_y[y+4]*sZY[zi] + pa_y[y+4]*d2y;
                float zx = pb_x[x+4]*sZX[zi] + pa_x[x+4]*d2x;
                sZY[zi] = zy; sZX[zi] = zx;
                float wnew = sV2[zi]*(d2y + zy + d2x + zx) + 2.f*wc - nxt[w];
                if (y == sly && x == slx) wnew += sV2[zi] * sAmp[t];
                nxt[w] = wnew;
            }
        }
        __syncthreads();

        // ---- record + export + release ----
        if (rofs >= 0) out[rofs + t] = nxt[rIdx];
        if (t < NT-1) {
            if (tid < 880)
                __hip_atomic_store(&strips[(size_t)((t&1)*256 + bid)*880 + tid],
                                   nxt[exp_src], __ATOMIC_RELAXED,
                                   __HIP_MEMORY_SCOPE_AGENT);
            __builtin_amdgcn_s_waitcnt(0);   // drain this wave's stores
            __syncthreads();                 // all waves' stores drained
            if (tid == 0)
                __hip_atomic_store(&flags[bid], t+1, __ATOMIC_RELEASE,
                                   __HIP_MEMORY_SCOPE_AGENT);
        }
        float* tmp = cur; cur = nxt; nxt = tmp;
    }
}

extern "C" void kernel_launch(void* const* d_in, const int* in_sizes, int n_in,
                              void* d_out, int out_size, void* d_ws, size_t ws_size,
                              hipStream_t stream) {
    const float* v    = (const float*)d_in[0];
    const float* amp  = (const float*)d_in[1];
    const int*   sloc = (const int*)d_in[2];
    const int*   rloc = (const int*)d_in[3];
    float* out = (float*)d_out;

    int*   flags  = (int*)d_ws;
    float* strips = (float*)((char*)d_ws + 1024);

    hipMemsetAsync(flags, 0, 1024, stream);
    kWave<<<256, NTH, 0, stream>>>(v, amp, sloc, rloc, out, flags, strips);
}

// Round 7
// 767.156 us; speedup vs baseline: 1.1131x; 1.1131x over previous
//
#include <hip/hip_runtime.h>

#define NVEL  400
#define PMLW  20
#define NSIDE 440
#define BATCH 4
#define NT    100
#define NREC  100

#define TS 55              // tile side; 8x8 tiles x 4 batches = 256 blocks (1/CU)
#define GT 8
#define WP 65              // wf LDS pitch
#define PYP 56             // psiy rows -2..56 (59) x cols 0..54
#define PXP 60             // psix rows 0..54 x cols -2..56 (59)
#define ZP  56

#define C1f (1.0f/48.0f)   // 1/(12*dh)
#define C2f (1.0f/192.0f)  // 1/(12*dh*dh)
#define NTH 1024

#define WIDX(y,x) (((y)+4)*WP + ((x)+4))

__global__ __launch_bounds__(NTH, 1) void kWave(
    const float* __restrict__ v, const float* __restrict__ amp,
    const int* __restrict__ sloc, const int* __restrict__ rloc,
    float* __restrict__ out, int* __restrict__ flags, float* __restrict__ strips)
{
    __shared__ float sWF0[63*WP], sWF1[63*WP];
    __shared__ float sPY[59*PYP];
    __shared__ float sPX[TS*PXP];
    __shared__ float sZY[TS*ZP], sZX[TS*ZP], sV2[TS*ZP];
    __shared__ float pa_y[63], pb_y[63], pa_x[63], pb_x[63];
    __shared__ float sAmp[NT];

    const int tid  = threadIdx.x;
    const int lane = tid & 63;
    const int wv   = tid >> 6;          // wave id 0..15
    const int bid = blockIdx.x;
    const int b   = bid >> 6;
    const int tl  = bid & 63;
    const int tyi = tl >> 3, txi = tl & 7;
    const int by0 = tyi*TS, bx0 = txi*TS;
    const int nbN = (tyi > 0)    ? bid - GT : -1;
    const int nbS = (tyi < GT-1) ? bid + GT : -1;
    const int nbW = (txi > 0)    ? bid - 1  : -1;
    const int nbE = (txi < GT-1) ? bid + 1  : -1;

    // ---- init LDS state ----
    for (int i = tid; i < 63*WP; i += NTH) { sWF0[i] = 0.f; sWF1[i] = 0.f; }
    for (int i = tid; i < 59*PYP; i += NTH) sPY[i] = 0.f;
    for (int i = tid; i < TS*PXP; i += NTH) sPX[i] = 0.f;
    for (int i = tid; i < TS*ZP; i += NTH) { sZY[i] = 0.f; sZX[i] = 0.f; }
    for (int i = tid; i < TS*TS; i += NTH) {
        int y = i/TS, x = i - y*TS;
        int cy = min(max(by0 + y - PMLW, 0), NVEL-1);
        int cx = min(max(bx0 + x - PMLW, 0), NVEL-1);
        float vv = v[cy*NVEL + cx];
        sV2[y*ZP + x] = vv*vv*(float)(0.0008*0.0008);
    }
    if (tid < 63) {
        const float smax = (float)(3.0*2600.0*6.907755278982137/160.0);
        float gy = (float)(by0 + tid - 4);
        float dy = fmaxf(fminf(fmaxf((20.f-gy)/20.f,0.f),1.f),
                         fminf(fmaxf((gy-419.f)/20.f,0.f),1.f));
        float bby = expf(-smax*dy*dy*0.0008f);
        pb_y[tid] = bby; pa_y[tid] = bby - 1.f;
        float gx = (float)(bx0 + tid - 4);
        float dx = fmaxf(fminf(fmaxf((20.f-gx)/20.f,0.f),1.f),
                         fminf(fmaxf((gx-419.f)/20.f,0.f),1.f));
        float bbx = expf(-smax*dx*dx*0.0008f);
        pb_x[tid] = bbx; pa_x[tid] = bbx - 1.f;
    }
    if (tid < NT) sAmp[tid] = amp[b*NT + tid];

    const int sly = sloc[b*2]   + PMLW - by0;
    const int slx = sloc[b*2+1] + PMLW - bx0;

    int rofs = -1, rIdx = 0;
    if (tid < NREC) {
        int gry = rloc[(b*NREC+tid)*2]   + PMLW;
        int grx = rloc[(b*NREC+tid)*2+1] + PMLW;
        if (gry >= by0 && gry < by0+TS && grx >= bx0 && grx < bx0+TS) {
            rofs = (b*NREC+tid)*NT;
            rIdx = WIDX(gry-by0, grx-bx0);
        }
    }

    // import descriptors (one strip element per thread, tid<880).
    // Slots: 0=rows0..3, 1=rows51..54 (c-fast), 2=cols0..3, 3=cols51..54 (r-fast).
    int imp_nb = -1, imp_src = 0, imp_dst = 0;
    if (tid < 880) {
        int e = tid/220, j = tid - e*220;
        if (e == 0)      { int r=j/55, c=j-55*r; imp_nb=nbN; imp_src=1*220+j; imp_dst=WIDX(r-4,c); }
        else if (e == 1) { int r=j/55, c=j-55*r; imp_nb=nbS; imp_src=0*220+j; imp_dst=WIDX(55+r,c); }
        else if (e == 2) { int r=j&3,  c=j>>2;   imp_nb=nbW; imp_src=3*220+j; imp_dst=WIDX(c,r-4); }
        else             { int r=j&3,  c=j>>2;   imp_nb=nbE; imp_src=2*220+j; imp_dst=WIDX(c,55+r); }
    }
    __syncthreads();

    float* cur = sWF0;
    float* nxt = sWF1;

#define PHASE2_BODY(yy, xx) {                                                   \
    int y = (yy), x = (xx);                                                     \
    int w = WIDX(y, x);                                                         \
    float wc = cur[w];                                                          \
    float d2y = (-(cur[w-2*WP] + cur[w+2*WP])                                   \
                 + 16.f*(cur[w-WP] + cur[w+WP]) - 30.f*wc) * C2f                \
              + (sPY[y*PYP+x] - sPY[(y+4)*PYP+x]                                \
                 + 8.f*(sPY[(y+3)*PYP+x] - sPY[(y+1)*PYP+x])) * C1f;            \
    float d2x = (-(cur[w-2] + cur[w+2])                                         \
                 + 16.f*(cur[w-1] + cur[w+1]) - 30.f*wc) * C2f                  \
              + (sPX[y*PXP+x] - sPX[y*PXP+x+4]                                  \
                 + 8.f*(sPX[y*PXP+x+3] - sPX[y*PXP+x+1])) * C1f;                \
    int zi = y*ZP + x;                                                          \
    float zy = pb_y[y+4]*sZY[zi] + pa_y[y+4]*d2y;                               \
    float zx = pb_x[x+4]*sZX[zi] + pa_x[x+4]*d2x;                               \
    sZY[zi] = zy; sZX[zi] = zx;                                                 \
    float wnew = sV2[zi]*(d2y + zy + d2x + zx) + 2.f*wc - nxt[w];               \
    if (y == sly && x == slx) wnew += sV2[zi] * sAmp[t];                        \
    nxt[w] = wnew; }

    for (int t = 0; t < NT; ++t) {
        // ---- A: poll (flag published early last step) + ISSUE halo loads ----
        float hval = 0.f;
        if (t > 0 && imp_nb >= 0) {
            int spin = 0;
            while (__hip_atomic_load(&flags[imp_nb], __ATOMIC_RELAXED,
                                     __HIP_MEMORY_SCOPE_AGENT) < t
                   && spin < 2000000) { __builtin_amdgcn_s_sleep(1); ++spin; }
            hval = __hip_atomic_load(
                &strips[(size_t)(((t-1)&1)*256 + imp_nb)*880 + imp_src],
                __ATOMIC_RELAXED, __HIP_MEMORY_SCOPE_AGENT);
        }
        asm volatile("" ::: "memory");   // pin load issue above psi-core

        // ---- B: psi-core (rows/cols 2..52; owned wf only, always in-domain) ----
        #pragma unroll
        for (int k = 0; k < 4; ++k) {
            int r = 2 + wv + 16*k;
            if (r <= 52 && lane < 55) {
                int w = WIDX(r, lane);
                float d1 = (cur[w-2*WP] - cur[w+2*WP]
                            + 8.f*(cur[w+WP] - cur[w-WP])) * C1f;
                int pi = (r+2)*PYP + lane;
                sPY[pi] = pb_y[r+4]*sPY[pi] + pa_y[r+4]*d1;
            }
        }
        #pragma unroll
        for (int k = 0; k < 4; ++k) {
            int y = wv + 16*k;
            if (y < 55 && lane < 51) {
                int c = lane + 2;
                int w = WIDX(y, c);
                float d1 = (cur[w-2] - cur[w+2]
                            + 8.f*(cur[w+1] - cur[w-1])) * C1f;
                int pi = y*PXP + c + 2;
                sPX[pi] = pb_x[c+4]*sPX[pi] + pa_x[c+4]*d1;
            }
        }

        // ---- C: commit imported halo (auto-waitcnt lands here) ----
        if (t > 0 && imp_nb >= 0) cur[imp_dst] = hval;
        __syncthreads();                                   // [b1]

        // ---- D: psi-rim (rows/cols -2..1 and 53..56; needs halo) ----
        if (wv < 8) {
            int r = (wv < 4) ? wv-2 : wv+49;
            if (lane < 55) {
                int w = WIDX(r, lane);
                float d1 = (cur[w-2*WP] - cur[w+2*WP]
                            + 8.f*(cur[w+WP] - cur[w-WP])) * C1f;
                int gy = by0 + r;
                int pi = (r+2)*PYP + lane;
                float val = 0.f;
                if (gy >= 0 && gy < NSIDE) val = pb_y[r+4]*sPY[pi] + pa_y[r+4]*d1;
                sPY[pi] = val;
            }
        } else {
            int c = (wv < 12) ? wv-10 : wv+41;
            if (lane < 55) {
                int y = lane;
                int w = WIDX(y, c);
                float d1 = (cur[w-2] - cur[w+2]
                            + 8.f*(cur[w+1] - cur[w-1])) * C1f;
                int gx = bx0 + c;
                int pi = y*PXP + c + 2;
                float val = 0.f;
                if (gx >= 0 && gx < NSIDE) val = pb_x[c+4]*sPX[pi] + pa_x[c+4]*d1;
                sPX[pi] = val;
            }
        }
        __syncthreads();                                   // [b2]

        // ---- E: interior-rim (816 frame cells) ----
        if (tid < 816) {
            int yy, xx;
            if (tid < 440) { int k = tid/55; xx = tid - 55*k; yy = (k < 4) ? k : (k+47); }
            else { int q = tid - 440; int r8 = q >> 3; int c8 = q & 7;
                   yy = r8 + 4; xx = (c8 < 4) ? c8 : (c8+47); }
            PHASE2_BODY(yy, xx)
        }
        __syncthreads();                                   // [b3]

        // ---- F: wave15 exports rim + publishes flag EARLY; others do core ----
        if (wv == 15) {
            if (t < NT-1) {
                float ev[14];
                #pragma unroll
                for (int k = 0; k < 14; ++k) {
                    int i = lane + 64*k;
                    if (i < 880) {
                        int e = (i>=660)?3:(i>=440)?2:(i>=220)?1:0;
                        int j = i - 220*e;
                        int src;
                        if (e < 2) {
                            int r = (j>=165)+(j>=110)+(j>=55);
                            int c = j - 55*r;
                            src = (e==0) ? WIDX(r,c) : WIDX(51+r,c);
                        } else {
                            int r = j & 3, c = j >> 2;
                            src = (e==2) ? WIDX(c,r) : WIDX(c,51+r);
                        }
                        ev[k] = nxt[src];
                    }
                }
                #pragma unroll
                for (int k = 0; k < 14; ++k) {
                    int i = lane + 64*k;
                    if (i < 880)
                        __hip_atomic_store(
                            &strips[(size_t)((t&1)*256 + bid)*880 + i], ev[k],
                            __ATOMIC_RELAXED, __HIP_MEMORY_SCOPE_AGENT);
                }
                __builtin_amdgcn_s_waitcnt(0);
                if (lane == 0)
                    __hip_atomic_store(&flags[bid], t+1, __ATOMIC_RELEASE,
                                       __HIP_MEMORY_SCOPE_AGENT);
            }
        } else {
            // interior-core [4,50]^2 = 2209 cells over 960 threads
            #pragma unroll
            for (int k = 0; k < 3; ++k) {
                int idx = tid + 960*k;
                if (idx < 2209) {
                    int yy = idx/47, xx = idx - 47*yy;
                    PHASE2_BODY(yy+4, xx+4)
                }
            }
        }
        __syncthreads();                                   // [b4]

        // ---- record receivers of this step ----
        if (rofs >= 0) out[rofs + t] = nxt[rIdx];

        float* tmp = cur; cur = nxt; nxt = tmp;
    }
#undef PHASE2_BODY
}

extern "C" void kernel_launch(void* const* d_in, const int* in_sizes, int n_in,
                              void* d_out, int out_size, void* d_ws, size_t ws_size,
                              hipStream_t stream) {
    const float* v    = (const float*)d_in[0];
    const float* amp  = (const float*)d_in[1];
    const int*   sloc = (const int*)d_in[2];
    const int*   rloc = (const int*)d_in[3];
    float* out = (float*)d_out;

    int*   flags  = (int*)d_ws;
    float* strips = (float*)((char*)d_ws + 1024);

    hipMemsetAsync(flags, 0, 1024, stream);
    kWave<<<256, NTH, 0, stream>>>(v, amp, sloc, rloc, out, flags, strips);
}